// Round 15
// baseline (55.258 us; speedup 1.0000x reference)
//
#include <hip/hip_runtime.h>
#include <math.h>

#define N_NODES 8192
#define D 256
#define HID 128
#define S_SEG 256
#define MAXC 64
#define HFT_STR 144  // bytes per HfT row
#define PB_STR 144   // bytes per Pbf16 row
#define PB_LO 9216   // lo block offset within P buffer

typedef __attribute__((ext_vector_type(8))) short short8;
typedef __attribute__((ext_vector_type(4))) float f32x4;
typedef unsigned short u16;
typedef unsigned int u32;

__device__ __forceinline__ u16 f2bf(float f) {
  u32 u = __float_as_uint(f);
  u32 r = (u + 0x7fffu + ((u >> 16) & 1u)) >> 16;
  return (u16)r;
}
__device__ __forceinline__ float bf2f(u16 b) {
  return __uint_as_float(((u32)b) << 16);
}
__device__ __forceinline__ int4 pack8(float4 x, float4 y) {
  int4 v;
  v.x = (int)(((u32)f2bf(x.y) << 16) | f2bf(x.x));
  v.y = (int)(((u32)f2bf(x.w) << 16) | f2bf(x.z));
  v.z = (int)(((u32)f2bf(y.y) << 16) | f2bf(y.x));
  v.w = (int)(((u32)f2bf(y.w) << 16) | f2bf(y.z));
  return v;
}

// raw barrier: drain LDS ops only; global (weight-prefetch) loads stay in
// flight across the barrier (register-destined -> no cross-wave visibility
// needed). __syncthreads would drain vmcnt(0) and serialize the prefetch.
__device__ __forceinline__ void bar_lds() {
  asm volatile("s_waitcnt lgkmcnt(0)" ::: "memory");
  __builtin_amdgcn_s_barrier();
  asm volatile("" ::: "memory");
}

// ---------------- prep: block 0 = segment meta; blocks 1..56 = weight cvt ----
struct CvtJobs {
  const float* src[7];
  u16* dst[7];
  int n4[7];
};
__global__ __launch_bounds__(256) void prep(const int* __restrict__ batch,
                                            int* __restrict__ sstart,
                                            int* __restrict__ scount, CvtJobs jb) {
  if (blockIdx.x == 0) {
    __shared__ int cntS[S_SEG];
    __shared__ int startS[S_SEG];
    const int t = threadIdx.x;
    cntS[t] = 0;
    startS[t] = 0;
    __syncthreads();
    const int base = t * 32;
    int pb = (base == 0) ? -1 : batch[base - 1];
    for (int i = 0; i < 32; ++i) {
      int b = batch[base + i];
      atomicAdd(&cntS[b], 1);
      if (b != pb) startS[b] = base + i;
      pb = b;
    }
    __syncthreads();
    scount[t] = cntS[t];
    sstart[t] = startS[t];
  } else {
    const int bid = blockIdx.x - 1;
    const int job = bid >> 3, chunk = bid & 7;
    const float* s = jb.src[job];
    u16* d = jb.dst[job];
    const int n4 = jb.n4[job];
    for (int i = chunk * 256 + threadIdx.x; i < n4; i += 2048) {
      float4 v = ((const float4*)s)[i];
      ushort4 o;
      o.x = f2bf(v.x); o.y = f2bf(v.y); o.z = f2bf(v.z); o.w = f2bf(v.w);
      ((ushort4*)d)[i] = o;
    }
  }
}

// ---- weight-fragment prefetch: 16 cols x K for this wave's colgroup ----
template <int KST>
__device__ __forceinline__ void loadW(short8* w, const u16* __restrict__ Wg,
                                      int col, int K, int lane) {
  const u16* base = Wg + (size_t)col * K + ((lane >> 4) * 8);
#pragma unroll
  for (int kk = 0; kk < KST; ++kk) w[kk] = *(const short8*)(base + kk * 32);
}

// ---- MLP phase with preloaded weights; wave owns ONE colgroup ----
// MODE: 0 LDS out; 3 LDS hi/lo out; 4 LDS row-major + transposed copy (HfT).
template <int KST, int ACT, int ISTR, int OSTR, int MODE, int MG>
__device__ __forceinline__ void mlp_phase(
    const u16* ldsIn, u16* ldsOut, u16* ldsOut2, const short8* wreg,
    const float* __restrict__ bias, int cg, int rows, int lane, int wave) {
  const int nrt = (rows + 31) >> 5;
  const int col = cg * 16 + (lane & 15);
  const float b = bias[col];
  int rt0, rt1;
  if constexpr (MG == 16) {
    rt0 = 0; rt1 = nrt;
  } else {
    rt0 = wave >> 3;
    rt1 = (rt0 < nrt) ? rt0 + 1 : rt0;
  }
  for (int rt = rt0; rt < rt1; ++rt) {
    short8 af[2][KST];
#pragma unroll
    for (int m = 0; m < 2; ++m)
#pragma unroll
      for (int kk = 0; kk < KST; ++kk) {
        const int r = rt * 32 + m * 16 + (lane & 15);
        const int sl = kk * 4 + (lane >> 4);
        af[m][kk] = *(const short8*)((const char*)ldsIn + r * ISTR +
                                     ((sl ^ (r & 7)) * 16));
      }
    f32x4 acc0 = {0.f, 0.f, 0.f, 0.f}, acc1 = {0.f, 0.f, 0.f, 0.f};
    __builtin_amdgcn_s_setprio(1);
#pragma unroll
    for (int kk = 0; kk < KST; ++kk) {
      acc0 = __builtin_amdgcn_mfma_f32_16x16x32_bf16(af[0][kk], wreg[kk], acc0, 0, 0, 0);
      acc1 = __builtin_amdgcn_mfma_f32_16x16x32_bf16(af[1][kk], wreg[kk], acc1, 0, 0, 0);
    }
    __builtin_amdgcn_s_setprio(0);
    const int rb = (lane >> 4) * 4;
#pragma unroll
    for (int m = 0; m < 2; ++m) {
      f32x4 a = m ? acc1 : acc0;
#pragma unroll
      for (int r4 = 0; r4 < 4; ++r4) {
        const int row = rt * 32 + m * 16 + rb + r4;
        if (row < rows) {
          float v = a[r4] + b;
          if (ACT) v = (v >= 0.f) ? v : 0.01f * v;
          if constexpr (MODE == 3) {
            const int byo =
                row * OSTR + (((col >> 3) ^ (row & 7)) * 16) + (col & 7) * 2;
            u16 hi = f2bf(v);
            *(u16*)((char*)ldsOut + byo) = hi;
            *(u16*)((char*)ldsOut2 + byo) = f2bf(v - bf2f(hi));
          } else if constexpr (MODE == 4) {
            u16 hv = f2bf(v);
            *(u16*)((char*)ldsOut + row * OSTR +
                    (((col >> 3) ^ (row & 7)) * 16) + (col & 7) * 2) = hv;
            *(u16*)((char*)ldsOut2 + col * HFT_STR + row * 2) = hv;
          } else {
            *(u16*)((char*)ldsOut + row * OSTR +
                    (((col >> 3) ^ (row & 7)) * 16) + (col & 7) * 2) = f2bf(v);
          }
        }
      }
    }
  }
}

// ---- legacy MLP layer (fallback path only) ----
template <int KST, int ACT, int ISTR, int OSTR, int MODE>
__device__ __forceinline__ void mlp16(
    const u16* ldsIn, u16* ldsOut, u16* ldsOut2, const u16* __restrict__ Wg,
    const float* __restrict__ bias, u16* __restrict__ gOut,
    u16* __restrict__ gOut2, int M, int K, int rows, int lane, int wave) {
  const int MG = M >> 4;
  const int npairs = ((rows + 31) >> 5) * MG;
  for (int p = wave; p < npairs; p += 16) {
    const int rt = p / MG, cg = p - rt * MG;
    short8 af[2][KST];
#pragma unroll
    for (int m = 0; m < 2; ++m)
#pragma unroll
      for (int kk = 0; kk < KST; ++kk) {
        const int r = rt * 32 + m * 16 + (lane & 15);
        const int sl = kk * 4 + (lane >> 4);
        af[m][kk] = *(const short8*)((const char*)ldsIn + r * ISTR +
                                     ((sl ^ (r & 7)) * 16));
      }
    const int col = cg * 16 + (lane & 15);
    short8 bfr[KST];
#pragma unroll
    for (int kk = 0; kk < KST; ++kk)
      bfr[kk] = *(const short8*)&Wg[(size_t)col * K + kk * 32 + (lane >> 4) * 8];
    f32x4 acc0 = {0.f, 0.f, 0.f, 0.f}, acc1 = {0.f, 0.f, 0.f, 0.f};
#pragma unroll
    for (int kk = 0; kk < KST; ++kk) {
      acc0 = __builtin_amdgcn_mfma_f32_16x16x32_bf16(af[0][kk], bfr[kk], acc0, 0, 0, 0);
      acc1 = __builtin_amdgcn_mfma_f32_16x16x32_bf16(af[1][kk], bfr[kk], acc1, 0, 0, 0);
    }
    const float b = bias[col];
    const int rb = (lane >> 4) * 4;
#pragma unroll
    for (int m = 0; m < 2; ++m) {
      f32x4 a = m ? acc1 : acc0;
#pragma unroll
      for (int r4 = 0; r4 < 4; ++r4) {
        const int row = rt * 32 + m * 16 + rb + r4;
        if (row < rows) {
          float v = a[r4] + b;
          if (ACT) v = (v >= 0.f) ? v : 0.01f * v;
          if constexpr (MODE == 2) {
            u16 hi = f2bf(v);
            gOut[(size_t)row * M + col] = hi;
            gOut2[(size_t)row * M + col] = f2bf(v - bf2f(hi));
          } else {
            u16 hv = f2bf(v);
            *(u16*)((char*)ldsOut + row * OSTR + (((col >> 3) ^ (row & 7)) * 16) +
                    (col & 7) * 2) = hv;
            if constexpr (MODE == 1) gOut[(size_t)row * M + col] = hv;
          }
        }
      }
    }
  }
}

// ---- seg_all: the whole network per segment in one block ----
__global__ __launch_bounds__(1024) void seg_all(
    const float* __restrict__ H, const u16* __restrict__ pw1,
    const float* __restrict__ pb1, const u16* __restrict__ pw2,
    const float* __restrict__ pb2, const u16* __restrict__ aw,
    const float* __restrict__ ab, const u16* __restrict__ rw1,
    const float* __restrict__ rb1, const u16* __restrict__ rw2,
    const float* __restrict__ rb2, const u16* __restrict__ gw1,
    const float* __restrict__ gb1, const u16* __restrict__ gw2,
    const float* __restrict__ gb2, const float* __restrict__ gw3,
    const float* __restrict__ gb3, const int* __restrict__ sstart,
    const int* __restrict__ scount, float* __restrict__ hpool,
    float* __restrict__ scores, u16* __restrict__ Hfg, u16* __restrict__ aHg,
    u16* __restrict__ aLg, u16* __restrict__ Hmg, u16* __restrict__ Hm2g,
    float* __restrict__ hgg) {
  __shared__ __align__(16) u16 bufX[MAXC * 256];  // H/Hf -> P -> g1
  __shared__ __align__(16) u16 bufY[MAXC * 256];  // phi1out -> attL -> rho1out
  __shared__ __align__(16) u16 attH[MAXC * 256];  // att hi -> Hm
  __shared__ __align__(16) u16 Tt[256 * 72];      // HfT -> Hm2
  __shared__ float hgs[MAXC];
  __shared__ float red[1024];
  __shared__ float part[1024];
  const int s = blockIdx.x, t = threadIdx.x;
  const int cnt = scount[s];
  const int r0 = sstart[s];
  const int wave = t >> 6, lane = t & 63;

  if (cnt == 0) {
    if (t < 256) hpool[(size_t)s * D + t] = 0.f;
    return;
  }

  if (cnt <= MAXC) {
    short8 wreg[8];
    const int cg16 = (wave + s) & 15;
    const int cg8 = ((wave & 7) + s) & 7;
    const int col16 = cg16 * 16 + (lane & 15);
    const int col8 = cg8 * 16 + (lane & 15);
    const int l15 = lane & 15;

    // ---- P0: prefetch phi1 weights + stage H ----
    loadW<8>(wreg, pw1, col16, D, lane);
    {
      const int r = t >> 4, p16 = t & 15;
      if (r < cnt) {
        const float4* src = (const float4*)&H[(size_t)(r0 + r) * D + p16 * 16];
#pragma unroll
        for (int i = 0; i < 2; ++i) {
          int4 v = pack8(src[2 * i], src[2 * i + 1]);
          const int sl = p16 * 2 + i;
          *(int4*)((char*)bufX + r * 512 + ((sl ^ (r & 7)) * 16)) = v;
        }
      }
    }
    bar_lds();
    // ---- P1: phi1 (bufX -> bufY) ----
    mlp_phase<8, 1, 512, 512, 0, 16>(bufX, bufY, nullptr, wreg, pb1, cg16, cnt, lane, wave);
    loadW<8>(wreg, pw2, col16, D, lane);
    bar_lds();
    // ---- P2: phi2 (bufY -> bufX = Hf, + Tt = HfT) ----
    mlp_phase<8, 1, 512, 512, 4, 16>(bufY, bufX, (u16*)Tt, wreg, pb2, cg16, cnt, lane, wave);
    loadW<8>(wreg, aw, col16, D, lane);
    bar_lds();
    // ---- P3: att projection (bufX -> attH hi, bufY lo) ----
    mlp_phase<8, 0, 512, 512, 3, 16>(bufX, attH, bufY, wreg, ab, cg16, cnt, lane, wave);
    loadW<8>(wreg, rw1, col16, D, lane);  // rho1 prefetch rides P4+P5
    bar_lds();
    // ---- P4: QK^T (k0-outer) + exp + in-wave row sums + P hi/lo write ----
    const int cp = (cnt + 15) & ~15;
    const int nt = cp >> 4;
    const int cpk = (cp <= 32) ? 32 : 64;
    if (wave < nt) {
      const int ti = wave;
      const int ra = ti * 16 + l15;
      f32x4 acc[4];
#pragma unroll
      for (int tj = 0; tj < 4; ++tj) acc[tj] = (f32x4){0.f, 0.f, 0.f, 0.f};
      __builtin_amdgcn_s_setprio(1);
#pragma unroll
      for (int k0 = 0; k0 < D; k0 += 32) {
        const int sg = (k0 >> 3) + (lane >> 4);
        short8 ah = *(const short8*)((const char*)attH + ra * 512 + ((sg ^ (ra & 7)) * 16));
        short8 av = *(const short8*)((const char*)bufY + ra * 512 + ((sg ^ (ra & 7)) * 16));
#pragma unroll
        for (int tj = 0; tj < 4; ++tj) {
          if (tj < nt) {
            const int rj = tj * 16 + l15;
            short8 bh = *(const short8*)((const char*)attH + rj * 512 + ((sg ^ (rj & 7)) * 16));
            short8 bv = *(const short8*)((const char*)bufY + rj * 512 + ((sg ^ (rj & 7)) * 16));
            acc[tj] = __builtin_amdgcn_mfma_f32_16x16x32_bf16(ah, bh, acc[tj], 0, 0, 0);
            acc[tj] = __builtin_amdgcn_mfma_f32_16x16x32_bf16(ah, bv, acc[tj], 0, 0, 0);
            acc[tj] = __builtin_amdgcn_mfma_f32_16x16x32_bf16(av, bh, acc[tj], 0, 0, 0);
          }
        }
      }
      __builtin_amdgcn_s_setprio(0);
      f32x4 rs = {0.f, 0.f, 0.f, 0.f};
#pragma unroll
      for (int tj = 0; tj < 4; ++tj) {
        if (tj < nt) {
          const bool jok = (tj * 16 + l15) < cnt;
#pragma unroll
          for (int r = 0; r < 4; ++r) acc[tj][r] = jok ? __expf(acc[tj][r]) : 0.f;
          float p0 = acc[tj][0], p1 = acc[tj][1], p2 = acc[tj][2], p3 = acc[tj][3];
#pragma unroll
          for (int o = 1; o <= 8; o <<= 1) {
            p0 += __shfl_xor(p0, o); p1 += __shfl_xor(p1, o);
            p2 += __shfl_xor(p2, o); p3 += __shfl_xor(p3, o);
          }
          rs[0] += p0; rs[1] += p1; rs[2] += p2; rs[3] += p3;
        }
      }
      const int rbase = ti * 16 + (lane >> 4) * 4;
#pragma unroll
      for (int tj = 0; tj < 4; ++tj) {
        if (tj < nt) {
          const int j = tj * 16 + l15;
#pragma unroll
          for (int r = 0; r < 4; ++r) {
            const float pv = acc[tj][r] / rs[r];
            const u16 hi = f2bf(pv);
            *(u16*)((char*)bufX + (rbase + r) * PB_STR + j * 2) = hi;
            *(u16*)((char*)bufX + PB_LO + (rbase + r) * PB_STR + j * 2) =
                f2bf(pv - bf2f(hi));
          }
        }
      }
    }
    if (cpk > cp) {  // zero P cols [cp,cpk) for rows [0,cp)
      for (int idx = t; idx < cp * 16; idx += 1024) {
        const int rr = idx >> 4, cc = cp + (idx & 15);
        *(u16*)((char*)bufX + rr * PB_STR + cc * 2) = 0;
        *(u16*)((char*)bufX + PB_LO + rr * PB_STR + cc * 2) = 0;
      }
    }
    if (cpk > cnt) {  // zero HfT cols [cnt,cpk)
      const int w3 = cpk - cnt;
      for (int idx = t; idx < 256 * w3; idx += 1024) {
        const int dd = idx / w3, cc = cnt + idx - (idx / w3) * w3;
        *(u16*)((char*)Tt + dd * HFT_STR + cc * 2) = 0;
      }
    }
    bar_lds();
    // ---- P5: PV via MFMA (bufX=P hi/lo, Tt=HfT) -> attH (Hm) ----
    {
      const int kst = cpk >> 5;
      for (int tt = wave; tt < nt * 16; tt += 16) {
        const int rt = tt >> 4, cg = tt & 15;
        const int arow = rt * 16 + l15;
        const int dcol = cg * 16 + l15;
        const int koct = (lane >> 4) * 8;
        f32x4 acc = {0.f, 0.f, 0.f, 0.f};
        __builtin_amdgcn_s_setprio(1);
        for (int ks = 0; ks < kst; ++ks) {
          const int kb = ks * 32 + koct;
          short8 ph = *(const short8*)((const char*)bufX + arow * PB_STR + kb * 2);
          short8 pl = *(const short8*)((const char*)bufX + PB_LO + arow * PB_STR + kb * 2);
          short8 hb = *(const short8*)((const char*)Tt + dcol * HFT_STR + kb * 2);
          acc = __builtin_amdgcn_mfma_f32_16x16x32_bf16(ph, hb, acc, 0, 0, 0);
          acc = __builtin_amdgcn_mfma_f32_16x16x32_bf16(pl, hb, acc, 0, 0, 0);
        }
        __builtin_amdgcn_s_setprio(0);
        const int rb = (lane >> 4) * 4;
#pragma unroll
        for (int r = 0; r < 4; ++r) {
          const int row = rt * 16 + rb + r;
          const int col = cg * 16 + l15;
          *(u16*)((char*)attH + row * 512 + (((col >> 3) ^ (row & 7)) * 16) +
                  (col & 7) * 2) = f2bf(acc[r]);
        }
      }
    }
    bar_lds();
    // ---- P6: rho1 (attH -> bufY) ----
    mlp_phase<8, 1, 512, 512, 0, 16>(attH, bufY, nullptr, wreg, rb1, cg16, cnt, lane, wave);
    loadW<8>(wreg, rw2, col16, D, lane);
    bar_lds();
    // ---- P7: rho2 (bufY -> Tt = Hm2, stride 512) ----
    mlp_phase<8, 1, 512, 512, 0, 16>(bufY, (u16*)Tt, nullptr, wreg, rb2, cg16, cnt, lane, wave);
    loadW<8>(wreg, gw1, col8, D, lane);
    bar_lds();
    // ---- P8: g1 (Tt -> bufX stride 256) + zero hgs ----
    if (t < 64) hgs[t] = 0.f;
    mlp_phase<8, 1, 512, 256, 0, 8>((u16*)Tt, bufX, nullptr, wreg, gb1, cg8, cnt, lane, wave);
    loadW<4>(wreg, gw2, col8, HID, lane);
    bar_lds();
    // ---- P9: g2 + fused gate3 (atomicAdd into hgs) ----
    {
      const int nrt = (cnt + 31) >> 5;
      const int rt = wave >> 3;
      if (rt < nrt) {
        short8 af2[2][4];
#pragma unroll
        for (int m = 0; m < 2; ++m)
#pragma unroll
          for (int kk = 0; kk < 4; ++kk) {
            const int r = rt * 32 + m * 16 + l15;
            const int sl = kk * 4 + (lane >> 4);
            af2[m][kk] = *(const short8*)((const char*)bufX + r * 256 +
                                          ((sl ^ (r & 7)) * 16));
          }
        f32x4 acc0 = {0.f, 0.f, 0.f, 0.f}, acc1 = {0.f, 0.f, 0.f, 0.f};
        __builtin_amdgcn_s_setprio(1);
#pragma unroll
        for (int kk = 0; kk < 4; ++kk) {
          acc0 = __builtin_amdgcn_mfma_f32_16x16x32_bf16(af2[0][kk], wreg[kk], acc0, 0, 0, 0);
          acc1 = __builtin_amdgcn_mfma_f32_16x16x32_bf16(af2[1][kk], wreg[kk], acc1, 0, 0, 0);
        }
        __builtin_amdgcn_s_setprio(0);
        const float b = gb2[col8];
        const float w3c = gw3[col8];
        const int rb = (lane >> 4) * 4;
#pragma unroll
        for (int m = 0; m < 2; ++m) {
          f32x4 a = m ? acc1 : acc0;
#pragma unroll
          for (int r4 = 0; r4 < 4; ++r4) {
            const int row = rt * 32 + m * 16 + rb + r4;
            float v = a[r4] + b;
            v = (v >= 0.f) ? v : 0.01f * v;
            float pp = v * w3c;
            pp += __shfl_xor(pp, 1);
            pp += __shfl_xor(pp, 2);
            pp += __shfl_xor(pp, 4);
            pp += __shfl_xor(pp, 8);
            if ((lane & 15) == 0 && row < cnt) atomicAdd(&hgs[row], pp);
          }
        }
      }
    }
    bar_lds();
    // ---- P10: segment softmax (per wave) + pool partials from Tt (Hm2) ----
    {
      const float hgv = (lane < cnt) ? hgs[lane] : -INFINITY;
      float m = hgv;
#pragma unroll
      for (int o = 32; o > 0; o >>= 1) m = fmaxf(m, __shfl_xor(m, o));
      float e = (lane < cnt) ? __expf(hgv - m) : 0.f;
      float sum = e;
#pragma unroll
      for (int o = 32; o > 0; o >>= 1) sum += __shfl_xor(sum, o);
      const float sc = e / sum;
      if (wave == 0 && lane < cnt) scores[r0 + lane] = sc;
      const int d = (wave & 3) * 64 + lane;
      const int g = wave >> 2;
      float acc = 0.f;
      for (int i = g; i < cnt; i += 4) {
        const float si = __shfl(sc, i);
        acc += si * bf2f(*(const u16*)((const char*)Tt + i * 512 +
                          (((d >> 3) ^ (i & 7)) * 16) + (d & 7) * 2));
      }
      part[g * 256 + d] = acc;
    }
    bar_lds();
    if (t < 256)
      hpool[(size_t)s * D + t] =
          part[t] + part[t + 256] + part[t + 512] + part[t + 768];
  } else {
    // ============ fallback (cnt > 64, practically never taken) ============
    for (int c0 = 0; c0 < cnt; c0 += 64) {
      const int rows = (cnt - c0) > 64 ? 64 : (cnt - c0);
      {
        const int r = t >> 4, p16 = t & 15;
        if (r < rows) {
          const float4* src = (const float4*)&H[(size_t)(r0 + c0 + r) * D + p16 * 16];
#pragma unroll
          for (int i = 0; i < 2; ++i) {
            int4 v = pack8(src[2 * i], src[2 * i + 1]);
            const int sl = p16 * 2 + i;
            *(int4*)((char*)bufX + r * 512 + ((sl ^ (r & 7)) * 16)) = v;
          }
        }
      }
      __syncthreads();
      mlp16<8, 1, 512, 512, 0>(bufX, bufY, nullptr, pw1, pb1, nullptr, nullptr, D, D, rows, lane, wave);
      __syncthreads();
      mlp16<8, 1, 512, 512, 1>(bufY, bufX, nullptr, pw2, pb2, Hfg + (size_t)(r0 + c0) * D, nullptr, D, D, rows, lane, wave);
      __syncthreads();
      mlp16<8, 0, 512, 512, 2>(bufX, nullptr, nullptr, aw, ab, aHg + (size_t)(r0 + c0) * D, aLg + (size_t)(r0 + c0) * D, D, D, rows, lane, wave);
      __syncthreads();
    }
    float* Pf = (float*)bufY;
    for (int i = 0; i < cnt; ++i) {
      const u16* ai = aHg + (size_t)(r0 + i) * D;
      const u16* li = aLg + (size_t)(r0 + i) * D;
      for (int j = t; j < cnt; j += 1024) {
        const u16* aj = aHg + (size_t)(r0 + j) * D;
        const u16* lj = aLg + (size_t)(r0 + j) * D;
        float acc = 0.f;
        for (int k = 0; k < D; ++k)
          acc += (bf2f(ai[k]) + bf2f(li[k])) * (bf2f(aj[k]) + bf2f(lj[k]));
        Pf[j] = acc;
      }
      __syncthreads();
      float pm = -INFINITY;
      for (int j = t; j < cnt; j += 1024) pm = fmaxf(pm, Pf[j]);
      red[t] = pm;
      __syncthreads();
      for (int o = 512; o > 0; o >>= 1) {
        if (t < o) red[t] = fmaxf(red[t], red[t + o]);
        __syncthreads();
      }
      const float m = red[0];
      __syncthreads();
      float ps = 0.f;
      for (int j = t; j < cnt; j += 1024) {
        const float e = __expf(Pf[j] - m);
        Pf[j] = e;
        ps += e;
      }
      red[t] = ps;
      __syncthreads();
      for (int o = 512; o > 0; o >>= 1) {
        if (t < o) red[t] += red[t + o];
        __syncthreads();
      }
      const float inv = 1.f / red[0];
      if (t < D) {
        float acc = 0.f;
        for (int j = 0; j < cnt; ++j)
          acc += Pf[j] * bf2f(Hfg[(size_t)(r0 + j) * D + t]);
        Hmg[(size_t)(r0 + i) * D + t] = f2bf(acc * inv);
      }
      __syncthreads();
    }
    for (int c0 = 0; c0 < cnt; c0 += 64) {
      const int rows = (cnt - c0) > 64 ? 64 : (cnt - c0);
      {
        const int r = t >> 4, p16 = t & 15;
        if (r < rows) {
          const int4* src = (const int4*)&Hmg[(size_t)(r0 + c0 + r) * D + p16 * 16];
#pragma unroll
          for (int i = 0; i < 2; ++i) {
            const int sl = p16 * 2 + i;
            *(int4*)((char*)bufX + r * 512 + ((sl ^ (r & 7)) * 16)) = src[i];
          }
        }
      }
      __syncthreads();
      mlp16<8, 1, 512, 512, 0>(bufX, bufY, nullptr, rw1, rb1, nullptr, nullptr, D, D, rows, lane, wave);
      __syncthreads();
      mlp16<8, 1, 512, 512, 1>(bufY, bufX, nullptr, rw2, rb2, Hm2g + (size_t)(r0 + c0) * D, nullptr, D, D, rows, lane, wave);
      __syncthreads();
      mlp16<8, 1, 512, 256, 0>(bufX, bufY, nullptr, gw1, gb1, nullptr, nullptr, HID, D, rows, lane, wave);
      __syncthreads();
      mlp16<4, 1, 256, 256, 0>(bufY, attH, nullptr, gw2, gb2, nullptr, nullptr, HID, HID, rows, lane, wave);
      __syncthreads();
      {
        const int i = t >> 4, p16 = t & 15;
        if (i < rows) {
          short8 hv = *(const short8*)((const char*)attH + i * 256 + ((p16 ^ (i & 7)) * 16));
          float sacc = 0.f;
#pragma unroll
          for (int q = 0; q < 8; ++q) sacc += bf2f((u16)hv[q]) * gw3[p16 * 8 + q];
          sacc += __shfl_xor(sacc, 1);
          sacc += __shfl_xor(sacc, 2);
          sacc += __shfl_xor(sacc, 4);
          sacc += __shfl_xor(sacc, 8);
          if (p16 == 0) hgg[r0 + c0 + i] = sacc + gb3[0];
        }
      }
      __syncthreads();
    }
    float pm = -INFINITY;
    for (int i = t; i < cnt; i += 1024) pm = fmaxf(pm, hgg[r0 + i]);
    red[t] = pm;
    __syncthreads();
    for (int o = 512; o > 0; o >>= 1) {
      if (t < o) red[t] = fmaxf(red[t], red[t + o]);
      __syncthreads();
    }
    const float m = red[0];
    __syncthreads();
    float ps = 0.f;
    for (int i = t; i < cnt; i += 1024) ps += __expf(hgg[r0 + i] - m);
    red[t] = ps;
    __syncthreads();
    for (int o = 512; o > 0; o >>= 1) {
      if (t < o) red[t] += red[t + o];
      __syncthreads();
    }
    const float inv = 1.f / red[0];
    for (int i = t; i < cnt; i += 1024)
      scores[r0 + i] = __expf(hgg[r0 + i] - m) * inv;
    const int h = t >> 8, d = t & 255;
    float acc = 0.f;
    for (int i = h; i < cnt; i += 4)
      acc += __expf(hgg[r0 + i] - m) * inv * bf2f(Hm2g[(size_t)(r0 + i) * D + d]);
    part[t] = acc;
    __syncthreads();
    if (t < 256)
      hpool[(size_t)s * D + t] =
          part[t] + part[t + 256] + part[t + 512] + part[t + 768];
  }
}

// ---------------------------------------------------------------------
extern "C" void kernel_launch(void* const* d_in, const int* in_sizes, int n_in,
                              void* d_out, int out_size, void* d_ws, size_t ws_size,
                              hipStream_t stream) {
  const float* H      = (const float*)d_in[0];
  const int*   batch  = (const int*)d_in[1];
  const float* phi_w1 = (const float*)d_in[2];
  const float* phi_b1 = (const float*)d_in[3];
  const float* phi_w2 = (const float*)d_in[4];
  const float* phi_b2 = (const float*)d_in[5];
  const float* att_w  = (const float*)d_in[6];
  const float* att_b  = (const float*)d_in[7];
  const float* rho_w1 = (const float*)d_in[8];
  const float* rho_b1 = (const float*)d_in[9];
  const float* rho_w2 = (const float*)d_in[10];
  const float* rho_b2 = (const float*)d_in[11];
  const float* g_w1   = (const float*)d_in[12];
  const float* g_b1   = (const float*)d_in[13];
  const float* g_w2   = (const float*)d_in[14];
  const float* g_b2   = (const float*)d_in[15];
  const float* g_w3   = (const float*)d_in[16];
  const float* g_b3   = (const float*)d_in[17];

  float* out_hpool  = (float*)d_out;
  float* out_scores = (float*)d_out + (size_t)S_SEG * D;

  char* w = (char*)d_ws;
  const size_t MB = 1u << 20;
  u16*   wb     = (u16*)(w);              // weights bf16 (<1MB)
  u16*   Hfg    = (u16*)(w + 1 * MB);     // fallback scratch
  u16*   aHg    = (u16*)(w + 5 * MB);
  u16*   aLg    = (u16*)(w + 9 * MB);
  u16*   Hmg    = (u16*)(w + 13 * MB);
  u16*   Hm2g   = (u16*)(w + 17 * MB);
  float* hgg    = (float*)(w + 21 * MB);
  int*   sstart = (int*)(w + 21 * MB + 64 * 1024);
  int*   scount = sstart + S_SEG;

  u16* phi_w1b = wb;
  u16* phi_w2b = wb + 65536;
  u16* att_wb  = wb + 2 * 65536;
  u16* rho_w1b = wb + 3 * 65536;
  u16* rho_w2b = wb + 4 * 65536;
  u16* g_w1b   = wb + 5 * 65536;
  u16* g_w2b   = wb + 5 * 65536 + 32768;

  CvtJobs jb;
  jb.src[0] = phi_w1; jb.dst[0] = phi_w1b; jb.n4[0] = 65536 / 4;
  jb.src[1] = phi_w2; jb.dst[1] = phi_w2b; jb.n4[1] = 65536 / 4;
  jb.src[2] = att_w;  jb.dst[2] = att_wb;  jb.n4[2] = 65536 / 4;
  jb.src[3] = rho_w1; jb.dst[3] = rho_w1b; jb.n4[3] = 65536 / 4;
  jb.src[4] = rho_w2; jb.dst[4] = rho_w2b; jb.n4[4] = 65536 / 4;
  jb.src[5] = g_w1;   jb.dst[5] = g_w1b;   jb.n4[5] = 32768 / 4;
  jb.src[6] = g_w2;   jb.dst[6] = g_w2b;   jb.n4[6] = 16384 / 4;

  prep<<<57, 256, 0, stream>>>(batch, sstart, scount, jb);

  seg_all<<<S_SEG, 1024, 0, stream>>>(
      H, phi_w1b, phi_b1, phi_w2b, phi_b2, att_wb, att_b, rho_w1b, rho_b1,
      rho_w2b, rho_b2, g_w1b, g_b1, g_w2b, g_b2, g_w3, g_b3, sstart, scount,
      out_hpool, out_scores, Hfg, aHg, aLg, Hmg, Hm2g, hgg);
}

// Round 16
// 49.594 us; speedup vs baseline: 1.1142x; 1.1142x over previous
//
#include <hip/hip_runtime.h>
#include <math.h>

#define N_NODES 8192
#define D 256
#define HID 128
#define S_SEG 256
#define MAXC 64
#define HFT_STR 144  // bytes per HfT row
#define PB_STR 144   // bytes per Pbf16 row
#define PB_LO 9216   // lo block offset within P buffer

typedef __attribute__((ext_vector_type(8))) short short8;
typedef __attribute__((ext_vector_type(4))) float f32x4;
typedef __attribute__((ext_vector_type(16))) float f32x16;
typedef unsigned short u16;
typedef unsigned int u32;

__device__ __forceinline__ u16 f2bf(float f) {
  u32 u = __float_as_uint(f);
  u32 r = (u + 0x7fffu + ((u >> 16) & 1u)) >> 16;
  return (u16)r;
}
__device__ __forceinline__ float bf2f(u16 b) {
  return __uint_as_float(((u32)b) << 16);
}
__device__ __forceinline__ int4 pack8(float4 x, float4 y) {
  int4 v;
  v.x = (int)(((u32)f2bf(x.y) << 16) | f2bf(x.x));
  v.y = (int)(((u32)f2bf(x.w) << 16) | f2bf(x.z));
  v.z = (int)(((u32)f2bf(y.y) << 16) | f2bf(y.x));
  v.w = (int)(((u32)f2bf(y.w) << 16) | f2bf(y.z));
  return v;
}

// ---------------- prep: block 0 = segment meta; blocks 1..56 = weight cvt ----
struct CvtJobs {
  const float* src[7];
  u16* dst[7];
  int n4[7];
};
__global__ __launch_bounds__(256) void prep(const int* __restrict__ batch,
                                            int* __restrict__ sstart,
                                            int* __restrict__ scount, CvtJobs jb) {
  if (blockIdx.x == 0) {
    __shared__ int cntS[S_SEG];
    __shared__ int startS[S_SEG];
    const int t = threadIdx.x;
    cntS[t] = 0;
    startS[t] = 0;
    __syncthreads();
    const int base = t * 32;
    int pb = (base == 0) ? -1 : batch[base - 1];
    for (int i = 0; i < 32; ++i) {
      int b = batch[base + i];
      atomicAdd(&cntS[b], 1);
      if (b != pb) startS[b] = base + i;
      pb = b;
    }
    __syncthreads();
    scount[t] = cntS[t];
    sstart[t] = startS[t];
  } else {
    const int bid = blockIdx.x - 1;
    const int job = bid >> 3, chunk = bid & 7;
    const float* s = jb.src[job];
    u16* d = jb.dst[job];
    const int n4 = jb.n4[job];
    for (int i = chunk * 256 + threadIdx.x; i < n4; i += 2048) {
      float4 v = ((const float4*)s)[i];
      ushort4 o;
      o.x = f2bf(v.x); o.y = f2bf(v.y); o.z = f2bf(v.z); o.w = f2bf(v.w);
      ((ushort4*)d)[i] = o;
    }
  }
}

// ---- 16-col weight fragment (16x16x32 path; g1/g2 + fallback) ----
template <int KST>
__device__ __forceinline__ void loadW(short8* w, const u16* __restrict__ Wg,
                                      int col, int K, int lane) {
  const u16* base = Wg + (size_t)col * K + ((lane >> 4) * 8);
#pragma unroll
  for (int kk = 0; kk < KST; ++kk) w[kk] = *(const short8*)(base + kk * 32);
}

// ---- half-K weight fragment for the 32x32x16 path: 32 cols, K half=128 ----
__device__ __forceinline__ void loadWh(short8* w, const u16* __restrict__ Wg,
                                       int col, int half, int kh) {
  const u16* base = Wg + (size_t)col * 256 + half * 128 + kh * 8;
#pragma unroll
  for (int kk = 0; kk < 8; ++kk) w[kk] = *(const short8*)(base + kk * 16);
}

// ---- 32x32x16 D->D MLP layer: wave owns 32 cols, loops rowtiles ----
// wpre holds half0 weights on entry; wcur = scratch for half1 (loaded here).
// MODE: 0 LDS out; 3 LDS hi/lo; 4 LDS row-major + transpose (HfT).
// A/B frag: idx = lane&31, k = (lane>>5)*8 + e. C/D: col = lane&31,
// row = (reg&3) + 8*(reg>>2) + 4*(lane>>5).
template <int ACT, int MODE>
__device__ __forceinline__ void mlp32(
    const u16* ldsIn, u16* ldsOut, u16* ldsOut2, short8* wpre, short8* wcur,
    const u16* __restrict__ Wg, const float* __restrict__ bias, int cp,
    int rows, int lane) {
  const int l31 = lane & 31;
  const int kh = lane >> 5;
  const int col = cp * 32 + l31;
  loadWh(wcur, Wg, col, 1, kh);  // half1 in flight under half0 MFMAs
  const float b = bias[col];
  const int nrt = (rows + 31) >> 5;
  const int r0r = l31, r1r = 32 + l31;
  f32x16 acc0, acc1;
#pragma unroll
  for (int i = 0; i < 16; ++i) { acc0[i] = 0.f; acc1[i] = 0.f; }
  __builtin_amdgcn_s_setprio(1);
#pragma unroll
  for (int kk = 0; kk < 8; ++kk) {
    const int slot = kk * 2 + kh;
    short8 a0 = *(const short8*)((const char*)ldsIn + r0r * 512 +
                                 ((slot ^ (r0r & 7)) * 16));
    acc0 = __builtin_amdgcn_mfma_f32_32x32x16_bf16(a0, wpre[kk], acc0, 0, 0, 0);
    if (nrt > 1) {
      short8 a1 = *(const short8*)((const char*)ldsIn + r1r * 512 +
                                   ((slot ^ (r1r & 7)) * 16));
      acc1 = __builtin_amdgcn_mfma_f32_32x32x16_bf16(a1, wpre[kk], acc1, 0, 0, 0);
    }
  }
#pragma unroll
  for (int kk = 0; kk < 8; ++kk) {
    const int slot = (8 + kk) * 2 + kh;
    short8 a0 = *(const short8*)((const char*)ldsIn + r0r * 512 +
                                 ((slot ^ (r0r & 7)) * 16));
    acc0 = __builtin_amdgcn_mfma_f32_32x32x16_bf16(a0, wcur[kk], acc0, 0, 0, 0);
    if (nrt > 1) {
      short8 a1 = *(const short8*)((const char*)ldsIn + r1r * 512 +
                                   ((slot ^ (r1r & 7)) * 16));
      acc1 = __builtin_amdgcn_mfma_f32_32x32x16_bf16(a1, wcur[kk], acc1, 0, 0, 0);
    }
  }
  __builtin_amdgcn_s_setprio(0);
#pragma unroll
  for (int rt = 0; rt < 2; ++rt) {
    if (rt == 1 && nrt < 2) break;
    const f32x16 A = rt ? acc1 : acc0;
#pragma unroll
    for (int reg = 0; reg < 16; ++reg) {
      const int row = rt * 32 + (reg & 3) + 8 * (reg >> 2) + 4 * kh;
      if (row < rows) {
        float v = A[reg] + b;
        if (ACT) v = (v >= 0.f) ? v : 0.01f * v;
        if constexpr (MODE == 3) {
          const int byo =
              row * 512 + (((col >> 3) ^ (row & 7)) * 16) + (col & 7) * 2;
          u16 hi = f2bf(v);
          *(u16*)((char*)ldsOut + byo) = hi;
          *(u16*)((char*)ldsOut2 + byo) = f2bf(v - bf2f(hi));
        } else if constexpr (MODE == 4) {
          u16 hv = f2bf(v);
          *(u16*)((char*)ldsOut + row * 512 + (((col >> 3) ^ (row & 7)) * 16) +
                  (col & 7) * 2) = hv;
          *(u16*)((char*)ldsOut2 + col * HFT_STR + row * 2) = hv;
        } else {
          *(u16*)((char*)ldsOut + row * 512 + (((col >> 3) ^ (row & 7)) * 16) +
                  (col & 7) * 2) = f2bf(v);
        }
      }
    }
  }
}

// ---- 16x16x32 MLP phase (g1 only in main path); wave>>3 = rowtile ----
template <int KST, int ACT, int ISTR, int OSTR, int MG>
__device__ __forceinline__ void mlp_phase(
    const u16* ldsIn, u16* ldsOut, const short8* wreg,
    const float* __restrict__ bias, int cg, int rows, int lane, int wave) {
  const int nrt = (rows + 31) >> 5;
  const int col = cg * 16 + (lane & 15);
  const float b = bias[col];
  int rt0, rt1;
  if constexpr (MG == 16) {
    rt0 = 0; rt1 = nrt;
  } else {
    rt0 = wave >> 3;
    rt1 = (rt0 < nrt) ? rt0 + 1 : rt0;
  }
  for (int rt = rt0; rt < rt1; ++rt) {
    short8 af[2][KST];
#pragma unroll
    for (int m = 0; m < 2; ++m)
#pragma unroll
      for (int kk = 0; kk < KST; ++kk) {
        const int r = rt * 32 + m * 16 + (lane & 15);
        const int sl = kk * 4 + (lane >> 4);
        af[m][kk] = *(const short8*)((const char*)ldsIn + r * ISTR +
                                     ((sl ^ (r & 7)) * 16));
      }
    f32x4 acc0 = {0.f, 0.f, 0.f, 0.f}, acc1 = {0.f, 0.f, 0.f, 0.f};
    __builtin_amdgcn_s_setprio(1);
#pragma unroll
    for (int kk = 0; kk < KST; ++kk) {
      acc0 = __builtin_amdgcn_mfma_f32_16x16x32_bf16(af[0][kk], wreg[kk], acc0, 0, 0, 0);
      acc1 = __builtin_amdgcn_mfma_f32_16x16x32_bf16(af[1][kk], wreg[kk], acc1, 0, 0, 0);
    }
    __builtin_amdgcn_s_setprio(0);
    const int rb = (lane >> 4) * 4;
#pragma unroll
    for (int m = 0; m < 2; ++m) {
      f32x4 a = m ? acc1 : acc0;
#pragma unroll
      for (int r4 = 0; r4 < 4; ++r4) {
        const int row = rt * 32 + m * 16 + rb + r4;
        if (row < rows) {
          float v = a[r4] + b;
          if (ACT) v = (v >= 0.f) ? v : 0.01f * v;
          *(u16*)((char*)ldsOut + row * OSTR + (((col >> 3) ^ (row & 7)) * 16) +
                  (col & 7) * 2) = f2bf(v);
        }
      }
    }
  }
}

// ---- legacy MLP layer (fallback path only) ----
template <int KST, int ACT, int ISTR, int OSTR, int MODE>
__device__ __forceinline__ void mlp16(
    const u16* ldsIn, u16* ldsOut, u16* ldsOut2, const u16* __restrict__ Wg,
    const float* __restrict__ bias, u16* __restrict__ gOut,
    u16* __restrict__ gOut2, int M, int K, int rows, int lane, int wave) {
  const int MG = M >> 4;
  const int npairs = ((rows + 31) >> 5) * MG;
  for (int p = wave; p < npairs; p += 16) {
    const int rt = p / MG, cg = p - rt * MG;
    short8 af[2][KST];
#pragma unroll
    for (int m = 0; m < 2; ++m)
#pragma unroll
      for (int kk = 0; kk < KST; ++kk) {
        const int r = rt * 32 + m * 16 + (lane & 15);
        const int sl = kk * 4 + (lane >> 4);
        af[m][kk] = *(const short8*)((const char*)ldsIn + r * ISTR +
                                     ((sl ^ (r & 7)) * 16));
      }
    const int col = cg * 16 + (lane & 15);
    short8 bfr[KST];
#pragma unroll
    for (int kk = 0; kk < KST; ++kk)
      bfr[kk] = *(const short8*)&Wg[(size_t)col * K + kk * 32 + (lane >> 4) * 8];
    f32x4 acc0 = {0.f, 0.f, 0.f, 0.f}, acc1 = {0.f, 0.f, 0.f, 0.f};
#pragma unroll
    for (int kk = 0; kk < KST; ++kk) {
      acc0 = __builtin_amdgcn_mfma_f32_16x16x32_bf16(af[0][kk], bfr[kk], acc0, 0, 0, 0);
      acc1 = __builtin_amdgcn_mfma_f32_16x16x32_bf16(af[1][kk], bfr[kk], acc1, 0, 0, 0);
    }
    const float b = bias[col];
    const int rb = (lane >> 4) * 4;
#pragma unroll
    for (int m = 0; m < 2; ++m) {
      f32x4 a = m ? acc1 : acc0;
#pragma unroll
      for (int r4 = 0; r4 < 4; ++r4) {
        const int row = rt * 32 + m * 16 + rb + r4;
        if (row < rows) {
          float v = a[r4] + b;
          if (ACT) v = (v >= 0.f) ? v : 0.01f * v;
          if constexpr (MODE == 2) {
            u16 hi = f2bf(v);
            gOut[(size_t)row * M + col] = hi;
            gOut2[(size_t)row * M + col] = f2bf(v - bf2f(hi));
          } else {
            u16 hv = f2bf(v);
            *(u16*)((char*)ldsOut + row * OSTR + (((col >> 3) ^ (row & 7)) * 16) +
                    (col & 7) * 2) = hv;
            if constexpr (MODE == 1) gOut[(size_t)row * M + col] = hv;
          }
        }
      }
    }
  }
}

// ---- seg_all: the whole network per segment in one block ----
__global__ __launch_bounds__(1024) void seg_all(
    const float* __restrict__ H, const u16* __restrict__ pw1,
    const float* __restrict__ pb1, const u16* __restrict__ pw2,
    const float* __restrict__ pb2, const u16* __restrict__ aw,
    const float* __restrict__ ab, const u16* __restrict__ rw1,
    const float* __restrict__ rb1, const u16* __restrict__ rw2,
    const float* __restrict__ rb2, const u16* __restrict__ gw1,
    const float* __restrict__ gb1, const u16* __restrict__ gw2,
    const float* __restrict__ gb2, const float* __restrict__ gw3,
    const float* __restrict__ gb3, const int* __restrict__ sstart,
    const int* __restrict__ scount, float* __restrict__ hpool,
    float* __restrict__ scores, u16* __restrict__ Hfg, u16* __restrict__ aHg,
    u16* __restrict__ aLg, u16* __restrict__ Hmg, u16* __restrict__ Hm2g,
    float* __restrict__ hgg) {
  __shared__ __align__(16) u16 bufX[MAXC * 256];  // H/Hf -> P -> g1
  __shared__ __align__(16) u16 bufY[MAXC * 256];  // phi1out -> attL -> rho1out
  __shared__ __align__(16) u16 attH[MAXC * 256];  // att hi -> Hm
  __shared__ __align__(16) u16 Tt[256 * 72];      // HfT -> Hm2
  __shared__ float hgs[MAXC];
  __shared__ float red[1024];
  __shared__ float part[1024];
  const int s = blockIdx.x, t = threadIdx.x;
  const int cnt = scount[s];
  const int r0 = sstart[s];
  const int wave = t >> 6, lane = t & 63;

  if (cnt == 0) {
    if (t < 256) hpool[(size_t)s * D + t] = 0.f;
    return;
  }

  if (cnt <= MAXC) {
    short8 wpre[8], wcur[8], wreg[8];
    const bool w8 = wave < 8;
    const int cp = (wave + s) & 7;  // 32-col group for the 32x32 path
    const int cg8 = ((wave & 7) + s) & 7;
    const int col8 = cg8 * 16 + (lane & 15);
    const int l15 = lane & 15;
    const int l31 = lane & 31;
    const int kh = lane >> 5;

    // ---- P0: prefetch phi1 half0 + stage H ----
    if (w8) loadWh(wpre, pw1, cp * 32 + l31, 0, kh);
    {
      const int r = t >> 4, p16 = t & 15;
      if (r < cnt) {
        const float4* src = (const float4*)&H[(size_t)(r0 + r) * D + p16 * 16];
#pragma unroll
        for (int i = 0; i < 2; ++i) {
          int4 v = pack8(src[2 * i], src[2 * i + 1]);
          const int sl = p16 * 2 + i;
          *(int4*)((char*)bufX + r * 512 + ((sl ^ (r & 7)) * 16)) = v;
        }
      }
    }
    __syncthreads();
    // ---- P1: phi1 (bufX -> bufY) ----
    if (w8) {
      mlp32<1, 0>(bufX, bufY, nullptr, wpre, wcur, pw1, pb1, cp, cnt, lane);
      loadWh(wpre, pw2, cp * 32 + l31, 0, kh);
    }
    __syncthreads();
    // ---- P2: phi2 (bufY -> bufX = Hf, + Tt = HfT) ----
    if (w8) {
      mlp32<1, 4>(bufY, bufX, (u16*)Tt, wpre, wcur, pw2, pb2, cp, cnt, lane);
      loadWh(wpre, aw, cp * 32 + l31, 0, kh);
    }
    __syncthreads();
    // ---- P3: att projection (bufX -> attH hi, bufY lo) ----
    if (w8) {
      mlp32<0, 3>(bufX, attH, bufY, wpre, wcur, aw, ab, cp, cnt, lane);
      loadWh(wpre, rw1, cp * 32 + l31, 0, kh);  // rides P4 + P5
    }
    __syncthreads();
    // ---- P4: QK^T + exp + in-wave row sums + P hi/lo write (row-owned) ----
    const int cpd = (cnt + 15) & ~15;
    const int nt = cpd >> 4;
    const int cpk = (cpd <= 32) ? 32 : 64;
    if (wave < nt) {
      const int ti = wave;
      const int ra = ti * 16 + l15;
      f32x4 evt[4];
      f32x4 rs = {0.f, 0.f, 0.f, 0.f};
#pragma unroll
      for (int tj = 0; tj < 4; ++tj) {
        if (tj < nt) {
          const int rj = tj * 16 + l15;
          f32x4 acc = {0.f, 0.f, 0.f, 0.f};
          __builtin_amdgcn_s_setprio(1);
#pragma unroll
          for (int k0 = 0; k0 < D; k0 += 32) {
            const int sg = (k0 >> 3) + (lane >> 4);
            short8 ah = *(const short8*)((const char*)attH + ra * 512 + ((sg ^ (ra & 7)) * 16));
            short8 av = *(const short8*)((const char*)bufY + ra * 512 + ((sg ^ (ra & 7)) * 16));
            short8 bh = *(const short8*)((const char*)attH + rj * 512 + ((sg ^ (rj & 7)) * 16));
            short8 bv = *(const short8*)((const char*)bufY + rj * 512 + ((sg ^ (rj & 7)) * 16));
            acc = __builtin_amdgcn_mfma_f32_16x16x32_bf16(ah, bh, acc, 0, 0, 0);
            acc = __builtin_amdgcn_mfma_f32_16x16x32_bf16(ah, bv, acc, 0, 0, 0);
            acc = __builtin_amdgcn_mfma_f32_16x16x32_bf16(av, bh, acc, 0, 0, 0);
          }
          __builtin_amdgcn_s_setprio(0);
          const bool jok = (tj * 16 + l15) < cnt;
          f32x4 ev;
#pragma unroll
          for (int r = 0; r < 4; ++r) ev[r] = jok ? __expf(acc[r]) : 0.f;
          evt[tj] = ev;
          float p0 = ev[0], p1 = ev[1], p2 = ev[2], p3 = ev[3];
#pragma unroll
          for (int o = 1; o <= 8; o <<= 1) {
            p0 += __shfl_xor(p0, o); p1 += __shfl_xor(p1, o);
            p2 += __shfl_xor(p2, o); p3 += __shfl_xor(p3, o);
          }
          rs[0] += p0; rs[1] += p1; rs[2] += p2; rs[3] += p3;
        }
      }
      const int rbase = ti * 16 + (lane >> 4) * 4;
#pragma unroll
      for (int tj = 0; tj < 4; ++tj) {
        if (tj < nt) {
          const int j = tj * 16 + l15;
#pragma unroll
          for (int r = 0; r < 4; ++r) {
            const float pv = evt[tj][r] / rs[r];
            const u16 hi = f2bf(pv);
            *(u16*)((char*)bufX + (rbase + r) * PB_STR + j * 2) = hi;
            *(u16*)((char*)bufX + PB_LO + (rbase + r) * PB_STR + j * 2) =
                f2bf(pv - bf2f(hi));
          }
        }
      }
    }
    if (cpk > cpd) {  // zero P cols [cpd,cpk) for rows [0,cpd)
      for (int idx = t; idx < cpd * 16; idx += 1024) {
        const int rr = idx >> 4, cc = cpd + (idx & 15);
        *(u16*)((char*)bufX + rr * PB_STR + cc * 2) = 0;
        *(u16*)((char*)bufX + PB_LO + rr * PB_STR + cc * 2) = 0;
      }
    }
    if (cpk > cnt) {  // zero HfT cols [cnt,cpk)
      const int w3 = cpk - cnt;
      for (int idx = t; idx < 256 * w3; idx += 1024) {
        const int dd = idx / w3, cc = cnt + idx - (idx / w3) * w3;
        *(u16*)((char*)Tt + dd * HFT_STR + cc * 2) = 0;
      }
    }
    __syncthreads();
    // ---- P5: PV via MFMA (bufX=P hi/lo, Tt=HfT) -> attH (Hm) ----
    {
      const int kst = cpk >> 5;
      for (int tt = wave; tt < nt * 16; tt += 16) {
        const int rt = tt >> 4, cg = tt & 15;
        const int arow = rt * 16 + l15;
        const int dcol = cg * 16 + l15;
        const int koct = (lane >> 4) * 8;
        f32x4 acc = {0.f, 0.f, 0.f, 0.f};
        __builtin_amdgcn_s_setprio(1);
        for (int ks = 0; ks < kst; ++ks) {
          const int kb = ks * 32 + koct;
          short8 ph = *(const short8*)((const char*)bufX + arow * PB_STR + kb * 2);
          short8 pl = *(const short8*)((const char*)bufX + PB_LO + arow * PB_STR + kb * 2);
          short8 hb = *(const short8*)((const char*)Tt + dcol * HFT_STR + kb * 2);
          acc = __builtin_amdgcn_mfma_f32_16x16x32_bf16(ph, hb, acc, 0, 0, 0);
          acc = __builtin_amdgcn_mfma_f32_16x16x32_bf16(pl, hb, acc, 0, 0, 0);
        }
        __builtin_amdgcn_s_setprio(0);
        const int rb = (lane >> 4) * 4;
#pragma unroll
        for (int r = 0; r < 4; ++r) {
          const int row = rt * 16 + rb + r;
          const int col = cg * 16 + l15;
          *(u16*)((char*)attH + row * 512 + (((col >> 3) ^ (row & 7)) * 16) +
                  (col & 7) * 2) = f2bf(acc[r]);
        }
      }
    }
    __syncthreads();
    // ---- P6: rho1 (attH -> bufY) ----
    if (w8) {
      mlp32<1, 0>(attH, bufY, nullptr, wpre, wcur, rw1, rb1, cp, cnt, lane);
      loadWh(wpre, rw2, cp * 32 + l31, 0, kh);
    }
    __syncthreads();
    // ---- P7: rho2 (bufY -> Tt = Hm2, stride 512) ----
    if (w8)
      mlp32<1, 0>(bufY, (u16*)Tt, nullptr, wpre, wcur, rw2, rb2, cp, cnt, lane);
    loadW<8>(wreg, gw1, col8, D, lane);
    __syncthreads();
    // ---- P8: g1 (Tt -> bufX stride 256) + zero hgs ----
    if (t < 64) hgs[t] = 0.f;
    mlp_phase<8, 1, 512, 256, 8>((u16*)Tt, bufX, wreg, gb1, cg8, cnt, lane, wave);
    loadW<4>(wreg, gw2, col8, HID, lane);
    __syncthreads();
    // ---- P9: g2 + fused gate3 (atomicAdd into hgs) ----
    {
      const int nrt = (cnt + 31) >> 5;
      const int rt = wave >> 3;
      if (rt < nrt) {
        short8 af2[2][4];
#pragma unroll
        for (int m = 0; m < 2; ++m)
#pragma unroll
          for (int kk = 0; kk < 4; ++kk) {
            const int r = rt * 32 + m * 16 + l15;
            const int sl = kk * 4 + (lane >> 4);
            af2[m][kk] = *(const short8*)((const char*)bufX + r * 256 +
                                          ((sl ^ (r & 7)) * 16));
          }
        f32x4 acc0 = {0.f, 0.f, 0.f, 0.f}, acc1 = {0.f, 0.f, 0.f, 0.f};
        __builtin_amdgcn_s_setprio(1);
#pragma unroll
        for (int kk = 0; kk < 4; ++kk) {
          acc0 = __builtin_amdgcn_mfma_f32_16x16x32_bf16(af2[0][kk], wreg[kk], acc0, 0, 0, 0);
          acc1 = __builtin_amdgcn_mfma_f32_16x16x32_bf16(af2[1][kk], wreg[kk], acc1, 0, 0, 0);
        }
        __builtin_amdgcn_s_setprio(0);
        const float b = gb2[col8];
        const float w3c = gw3[col8];
        const int rb = (lane >> 4) * 4;
#pragma unroll
        for (int m = 0; m < 2; ++m) {
          f32x4 a = m ? acc1 : acc0;
#pragma unroll
          for (int r4 = 0; r4 < 4; ++r4) {
            const int row = rt * 32 + m * 16 + rb + r4;
            float v = a[r4] + b;
            v = (v >= 0.f) ? v : 0.01f * v;
            float pp = v * w3c;
            pp += __shfl_xor(pp, 1);
            pp += __shfl_xor(pp, 2);
            pp += __shfl_xor(pp, 4);
            pp += __shfl_xor(pp, 8);
            if ((lane & 15) == 0 && row < cnt) atomicAdd(&hgs[row], pp);
          }
        }
      }
    }
    __syncthreads();
    // ---- P10: segment softmax (per wave) + pool partials from Tt (Hm2) ----
    {
      const float hgv = (lane < cnt) ? hgs[lane] : -INFINITY;
      float m = hgv;
#pragma unroll
      for (int o = 32; o > 0; o >>= 1) m = fmaxf(m, __shfl_xor(m, o));
      float e = (lane < cnt) ? __expf(hgv - m) : 0.f;
      float sum = e;
#pragma unroll
      for (int o = 32; o > 0; o >>= 1) sum += __shfl_xor(sum, o);
      const float sc = e / sum;
      if (wave == 0 && lane < cnt) scores[r0 + lane] = sc;
      const int d = (wave & 3) * 64 + lane;
      const int g = wave >> 2;
      float acc = 0.f;
      for (int i = g; i < cnt; i += 4) {
        const float si = __shfl(sc, i);
        acc += si * bf2f(*(const u16*)((const char*)Tt + i * 512 +
                          (((d >> 3) ^ (i & 7)) * 16) + (d & 7) * 2));
      }
      part[g * 256 + d] = acc;
    }
    __syncthreads();
    if (t < 256)
      hpool[(size_t)s * D + t] =
          part[t] + part[t + 256] + part[t + 512] + part[t + 768];
  } else {
    // ============ fallback (cnt > 64, practically never taken) ============
    for (int c0 = 0; c0 < cnt; c0 += 64) {
      const int rows = (cnt - c0) > 64 ? 64 : (cnt - c0);
      {
        const int r = t >> 4, p16 = t & 15;
        if (r < rows) {
          const float4* src = (const float4*)&H[(size_t)(r0 + c0 + r) * D + p16 * 16];
#pragma unroll
          for (int i = 0; i < 2; ++i) {
            int4 v = pack8(src[2 * i], src[2 * i + 1]);
            const int sl = p16 * 2 + i;
            *(int4*)((char*)bufX + r * 512 + ((sl ^ (r & 7)) * 16)) = v;
          }
        }
      }
      __syncthreads();
      mlp16<8, 1, 512, 512, 0>(bufX, bufY, nullptr, pw1, pb1, nullptr, nullptr, D, D, rows, lane, wave);
      __syncthreads();
      mlp16<8, 1, 512, 512, 1>(bufY, bufX, nullptr, pw2, pb2, Hfg + (size_t)(r0 + c0) * D, nullptr, D, D, rows, lane, wave);
      __syncthreads();
      mlp16<8, 0, 512, 512, 2>(bufX, nullptr, nullptr, aw, ab, aHg + (size_t)(r0 + c0) * D, aLg + (size_t)(r0 + c0) * D, D, D, rows, lane, wave);
      __syncthreads();
    }
    float* Pf = (float*)bufY;
    for (int i = 0; i < cnt; ++i) {
      const u16* ai = aHg + (size_t)(r0 + i) * D;
      const u16* li = aLg + (size_t)(r0 + i) * D;
      for (int j = t; j < cnt; j += 1024) {
        const u16* aj = aHg + (size_t)(r0 + j) * D;
        const u16* lj = aLg + (size_t)(r0 + j) * D;
        float acc = 0.f;
        for (int k = 0; k < D; ++k)
          acc += (bf2f(ai[k]) + bf2f(li[k])) * (bf2f(aj[k]) + bf2f(lj[k]));
        Pf[j] = acc;
      }
      __syncthreads();
      float pm = -INFINITY;
      for (int j = t; j < cnt; j += 1024) pm = fmaxf(pm, Pf[j]);
      red[t] = pm;
      __syncthreads();
      for (int o = 512; o > 0; o >>= 1) {
        if (t < o) red[t] = fmaxf(red[t], red[t + o]);
        __syncthreads();
      }
      const float m = red[0];
      __syncthreads();
      float ps = 0.f;
      for (int j = t; j < cnt; j += 1024) {
        const float e = __expf(Pf[j] - m);
        Pf[j] = e;
        ps += e;
      }
      red[t] = ps;
      __syncthreads();
      for (int o = 512; o > 0; o >>= 1) {
        if (t < o) red[t] += red[t + o];
        __syncthreads();
      }
      const float inv = 1.f / red[0];
      if (t < D) {
        float acc = 0.f;
        for (int j = 0; j < cnt; ++j)
          acc += Pf[j] * bf2f(Hfg[(size_t)(r0 + j) * D + t]);
        Hmg[(size_t)(r0 + i) * D + t] = f2bf(acc * inv);
      }
      __syncthreads();
    }
    for (int c0 = 0; c0 < cnt; c0 += 64) {
      const int rows = (cnt - c0) > 64 ? 64 : (cnt - c0);
      {
        const int r = t >> 4, p16 = t & 15;
        if (r < rows) {
          const int4* src = (const int4*)&Hmg[(size_t)(r0 + c0 + r) * D + p16 * 16];
#pragma unroll
          for (int i = 0; i < 2; ++i) {
            const int sl = p16 * 2 + i;
            *(int4*)((char*)bufX + r * 512 + ((sl ^ (r & 7)) * 16)) = src[i];
          }
        }
      }
      __syncthreads();
      mlp16<8, 1, 512, 512, 0>(bufX, bufY, nullptr, rw1, rb1, nullptr, nullptr, D, D, rows, lane, wave);
      __syncthreads();
      mlp16<8, 1, 512, 512, 1>(bufY, bufX, nullptr, rw2, rb2, Hm2g + (size_t)(r0 + c0) * D, nullptr, D, D, rows, lane, wave);
      __syncthreads();
      mlp16<8, 1, 512, 256, 0>(bufX, bufY, nullptr, gw1, gb1, nullptr, nullptr, HID, D, rows, lane, wave);
      __syncthreads();
      mlp16<4, 1, 256, 256, 0>(bufY, attH, nullptr, gw2, gb2, nullptr, nullptr, HID, HID, rows, lane, wave);
      __syncthreads();
      {
        const int i = t >> 4, p16 = t & 15;
        if (i < rows) {
          short8 hv = *(const short8*)((const char*)attH + i * 256 + ((p16 ^ (i & 7)) * 16));
          float sacc = 0.f;
#pragma unroll
          for (int q = 0; q < 8; ++q) sacc += bf2f((u16)hv[q]) * gw3[p16 * 8 + q];
          sacc += __shfl_xor(sacc, 1);
          sacc += __shfl_xor(sacc, 2);
          sacc += __shfl_xor(sacc, 4);
          sacc += __shfl_xor(sacc, 8);
          if (p16 == 0) hgg[r0 + c0 + i] = sacc + gb3[0];
        }
      }
      __syncthreads();
    }
    float pm = -INFINITY;
    for (int i = t; i < cnt; i += 1024) pm = fmaxf(pm, hgg[r0 + i]);
    red[t] = pm;
    __syncthreads();
    for (int o = 512; o > 0; o >>= 1) {
      if (t < o) red[t] = fmaxf(red[t], red[t + o]);
      __syncthreads();
    }
    const float m = red[0];
    __syncthreads();
    float ps = 0.f;
    for (int i = t; i < cnt; i += 1024) ps += __expf(hgg[r0 + i] - m);
    red[t] = ps;
    __syncthreads();
    for (int o = 512; o > 0; o >>= 1) {
      if (t < o) red[t] += red[t + o];
      __syncthreads();
    }
    const float inv = 1.f / red[0];
    for (int i = t; i < cnt; i += 1024)
      scores[r0 + i] = __expf(hgg[r0 + i] - m) * inv;
    const int h = t >> 8, d = t & 255;
    float acc = 0.f;
    for (int i = h; i < cnt; i += 4)
      acc += __expf(hgg[r0 + i] - m) * inv * bf2f(Hm2g[(size_t)(r0 + i) * D + d]);
    part[t] = acc;
    __syncthreads();
    if (t < 256)
      hpool[(size_t)s * D + t] =
          part[t] + part[t + 256] + part[t + 512] + part[t + 768];
  }
}

// ---------------------------------------------------------------------
extern "C" void kernel_launch(void* const* d_in, const int* in_sizes, int n_in,
                              void* d_out, int out_size, void* d_ws, size_t ws_size,
                              hipStream_t stream) {
  const float* H      = (const float*)d_in[0];
  const int*   batch  = (const int*)d_in[1];
  const float* phi_w1 = (const float*)d_in[2];
  const float* phi_b1 = (const float*)d_in[3];
  const float* phi_w2 = (const float*)d_in[4];
  const float* phi_b2 = (const float*)d_in[5];
  const float* att_w  = (const float*)d_in[6];
  const float* att_b  = (const float*)d_in[7];
  const float* rho_w1 = (const float*)d_in[8];
  const float* rho_b1 = (const float*)d_in[9];
  const float* rho_w2 = (const float*)d_in[10];
  const float* rho_b2 = (const float*)d_in[11];
  const float* g_w1   = (const float*)d_in[12];
  const float* g_b1   = (const float*)d_in[13];
  const float* g_w2   = (const float*)d_in[14];
  const float* g_b2   = (const float*)d_in[15];
  const float* g_w3   = (const float*)d_in[16];
  const float* g_b3   = (const float*)d_in[17];

  float* out_hpool  = (float*)d_out;
  float* out_scores = (float*)d_out + (size_t)S_SEG * D;

  char* w = (char*)d_ws;
  const size_t MB = 1u << 20;
  u16*   wb     = (u16*)(w);              // weights bf16 (<1MB)
  u16*   Hfg    = (u16*)(w + 1 * MB);     // fallback scratch
  u16*   aHg    = (u16*)(w + 5 * MB);
  u16*   aLg    = (u16*)(w + 9 * MB);
  u16*   Hmg    = (u16*)(w + 13 * MB);
  u16*   Hm2g   = (u16*)(w + 17 * MB);
  float* hgg    = (float*)(w + 21 * MB);
  int*   sstart = (int*)(w + 21 * MB + 64 * 1024);
  int*   scount = sstart + S_SEG;

  u16* phi_w1b = wb;
  u16* phi_w2b = wb + 65536;
  u16* att_wb  = wb + 2 * 65536;
  u16* rho_w1b = wb + 3 * 65536;
  u16* rho_w2b = wb + 4 * 65536;
  u16* g_w1b   = wb + 5 * 65536;
  u16* g_w2b   = wb + 5 * 65536 + 32768;

  CvtJobs jb;
  jb.src[0] = phi_w1; jb.dst[0] = phi_w1b; jb.n4[0] = 65536 / 4;
  jb.src[1] = phi_w2; jb.dst[1] = phi_w2b; jb.n4[1] = 65536 / 4;
  jb.src[2] = att_w;  jb.dst[2] = att_wb;  jb.n4[2] = 65536 / 4;
  jb.src[3] = rho_w1; jb.dst[3] = rho_w1b; jb.n4[3] = 65536 / 4;
  jb.src[4] = rho_w2; jb.dst[4] = rho_w2b; jb.n4[4] = 65536 / 4;
  jb.src[5] = g_w1;   jb.dst[5] = g_w1b;   jb.n4[5] = 32768 / 4;
  jb.src[6] = g_w2;   jb.dst[6] = g_w2b;   jb.n4[6] = 16384 / 4;

  prep<<<57, 256, 0, stream>>>(batch, sstart, scount, jb);

  seg_all<<<S_SEG, 1024, 0, stream>>>(
      H, phi_w1b, phi_b1, phi_w2b, phi_b2, att_wb, att_b, rho_w1b, rho_b1,
      rho_w2b, rho_b2, g_w1b, g_b1, g_w2b, g_b2, g_w3, g_b3, sstart, scount,
      out_hpool, out_scores, Hfg, aHg, aLg, Hmg, Hm2g, hgg);
}